// Round 1
// baseline (515933.008 us; speedup 1.0000x reference)
//
#include <hip/hip_runtime.h>
#include <hip/hip_cooperative_groups.h>

#define T_SEQ 8192
#define HDIM  2048
#define EDIM  2048

namespace cg = cooperative_groups;

// ---------------------------------------------------------------------------
// GEMM (NT): C[m][n] = sum_k A[m][k] * B[n][k] + bias[n]
// A: [M][K] row-major, B: [N][K] row-major. M,N % 64 == 0, K % 32 == 0.
// BM=BN=64, BK=32, 256 threads, 4x4 microtile per thread.
// ---------------------------------------------------------------------------
__global__ __launch_bounds__(256) void gemm_nt_bias(
    const float* __restrict__ A, const float* __restrict__ B,
    const float* __restrict__ bias, float* __restrict__ C,
    int M, int N, int K)
{
    constexpr int BK = 32;
    __shared__ float As[BK][64 + 4];   // +4 floats pad keeps 16B alignment, breaks bank stride
    __shared__ float Bs[BK][64 + 4];

    const int tx = threadIdx.x & 15;   // 0..15 -> N
    const int ty = threadIdx.x >> 4;   // 0..15 -> M
    const int m0 = blockIdx.y * 64;
    const int n0 = blockIdx.x * 64;

    float acc[4][4] = {};

    for (int kk = 0; kk < K; kk += BK) {
        #pragma unroll
        for (int p = 0; p < 8; ++p) {
            int idx = p * 256 + threadIdx.x;
            int r = idx >> 5;          // 0..63
            int c = idx & 31;          // 0..31
            As[c][r] = A[(size_t)(m0 + r) * K + kk + c];
            Bs[c][r] = B[(size_t)(n0 + r) * K + kk + c];
        }
        __syncthreads();
        #pragma unroll
        for (int k = 0; k < BK; ++k) {
            float4 a = *(const float4*)&As[k][ty * 4];
            float4 b = *(const float4*)&Bs[k][tx * 4];
            float av[4] = {a.x, a.y, a.z, a.w};
            float bv[4] = {b.x, b.y, b.z, b.w};
            #pragma unroll
            for (int i = 0; i < 4; ++i)
                #pragma unroll
                for (int j = 0; j < 4; ++j)
                    acc[i][j] = fmaf(av[i], bv[j], acc[i][j]);
        }
        __syncthreads();
    }

    float4 bb = *(const float4*)&bias[n0 + tx * 4];
    float bvv[4] = {bb.x, bb.y, bb.z, bb.w};
    #pragma unroll
    for (int i = 0; i < 4; ++i) {
        float4 o;
        o.x = acc[i][0] + bvv[0];
        o.y = acc[i][1] + bvv[1];
        o.z = acc[i][2] + bvv[2];
        o.w = acc[i][3] + bvv[3];
        *(float4*)&C[(size_t)(m0 + ty * 4 + i) * N + n0 + tx * 4] = o;
    }
}

// ---------------------------------------------------------------------------
// Recurrence: h_{t+1} = tanh(W_h h_t + xp[t]), Hs[t] = h_{t+1}.
// 256 blocks x 512 threads (8 waves). Block b owns rows b*8..b*8+7; wave w
// owns row b*8+w, with W_h row held in 32 VGPRs per lane (8 x float4).
// Cooperative launch; one grid.sync per step.
// ---------------------------------------------------------------------------
__global__ __launch_bounds__(512, 1) void rnn_recurrence(
    const float* __restrict__ Wh, const float* __restrict__ xp,
    const float* __restrict__ h0, float* __restrict__ Hs, int T)
{
    const int lane = threadIdx.x & 63;
    const int wid  = threadIdx.x >> 6;       // 0..7
    const int row  = blockIdx.x * 8 + wid;   // 0..HDIM-1

    // lane holds W_h[row][t8*256 + lane*4 + e], e=0..3, t8=0..7
    float4 w[8];
    const float4* wrow = (const float4*)(Wh + (size_t)row * HDIM);
    #pragma unroll
    for (int t8 = 0; t8 < 8; ++t8) w[t8] = wrow[t8 * 64 + lane];

    __shared__ float hsm[HDIM];
    cg::grid_group grid = cg::this_grid();

    const float* hprev = h0;
    for (int t = 0; t < T; ++t) {
        // stage h (8KB) into LDS: 512 threads x float4, fully coalesced/conflict-free
        ((float4*)hsm)[threadIdx.x] = ((const float4*)hprev)[threadIdx.x];
        __syncthreads();

        float accv = 0.0f;
        #pragma unroll
        for (int t8 = 0; t8 < 8; ++t8) {
            float4 h4 = ((const float4*)hsm)[t8 * 64 + lane];
            accv = fmaf(w[t8].x, h4.x, accv);
            accv = fmaf(w[t8].y, h4.y, accv);
            accv = fmaf(w[t8].z, h4.z, accv);
            accv = fmaf(w[t8].w, h4.w, accv);
        }
        #pragma unroll
        for (int off = 32; off > 0; off >>= 1) accv += __shfl_xor(accv, off);

        float z  = accv + xp[(size_t)t * HDIM + row];
        float hn = tanhf(z);
        if (lane == 0) Hs[(size_t)t * HDIM + row] = hn;

        __threadfence();   // make stores agent-visible before the barrier
        grid.sync();
        hprev = Hs + (size_t)t * HDIM;
    }
}

// ---------------------------------------------------------------------------
// Row softmax over EDIM=2048: one block (256 threads) per row, 8 elems/thread.
// ---------------------------------------------------------------------------
__global__ __launch_bounds__(256) void softmax_rows(
    const float* __restrict__ logits, float* __restrict__ out)
{
    const int row = blockIdx.x;
    const float4* in4 = (const float4*)(logits + (size_t)row * EDIM);
    float4* out4 = (float4*)(out + (size_t)row * EDIM);

    float4 v0 = in4[threadIdx.x];
    float4 v1 = in4[threadIdx.x + 256];

    float m = fmaxf(fmaxf(fmaxf(v0.x, v0.y), fmaxf(v0.z, v0.w)),
                    fmaxf(fmaxf(v1.x, v1.y), fmaxf(v1.z, v1.w)));
    #pragma unroll
    for (int off = 32; off > 0; off >>= 1) m = fmaxf(m, __shfl_xor(m, off));

    __shared__ float red[4];
    if ((threadIdx.x & 63) == 0) red[threadIdx.x >> 6] = m;
    __syncthreads();
    m = fmaxf(fmaxf(red[0], red[1]), fmaxf(red[2], red[3]));
    __syncthreads();   // before red[] reuse

    float e[8];
    e[0] = expf(v0.x - m); e[1] = expf(v0.y - m);
    e[2] = expf(v0.z - m); e[3] = expf(v0.w - m);
    e[4] = expf(v1.x - m); e[5] = expf(v1.y - m);
    e[6] = expf(v1.z - m); e[7] = expf(v1.w - m);

    float s = e[0] + e[1] + e[2] + e[3] + e[4] + e[5] + e[6] + e[7];
    #pragma unroll
    for (int off = 32; off > 0; off >>= 1) s += __shfl_xor(s, off);
    if ((threadIdx.x & 63) == 0) red[threadIdx.x >> 6] = s;
    __syncthreads();
    s = red[0] + red[1] + red[2] + red[3];

    float inv = 1.0f / s;
    out4[threadIdx.x]       = make_float4(e[0] * inv, e[1] * inv, e[2] * inv, e[3] * inv);
    out4[threadIdx.x + 256] = make_float4(e[4] * inv, e[5] * inv, e[6] * inv, e[7] * inv);
}

__global__ void copy_vec(const float* __restrict__ src, float* __restrict__ dst, int n)
{
    int i = blockIdx.x * blockDim.x + threadIdx.x;
    if (i < n) dst[i] = src[i];
}

// ---------------------------------------------------------------------------
extern "C" void kernel_launch(void* const* d_in, const int* in_sizes, int n_in,
                              void* d_out, int out_size, void* d_ws, size_t ws_size,
                              hipStream_t stream)
{
    const float* x  = (const float*)d_in[0];   // [T_SEQ][EDIM]
    const float* Wh = (const float*)d_in[1];   // [HDIM][HDIM]
    const float* Wx = (const float*)d_in[2];   // [HDIM][EDIM]
    const float* Wy = (const float*)d_in[3];   // [EDIM][HDIM]
    const float* Bh = (const float*)d_in[4];   // [HDIM]
    const float* By = (const float*)d_in[5];   // [EDIM]

    float* out    = (float*)d_out;
    float* hfinal = out;                 // [HDIM]
    float* hs     = out + HDIM;          // [T_SEQ][HDIM]: holds hs, then probs

    float* xp     = (float*)d_ws;                                    // [T_SEQ][HDIM]
    float* h0     = (float*)((char*)d_ws + (size_t)T_SEQ * HDIM * 4); // [HDIM]
    float* logits = xp;                  // reuse (xp dead after recurrence)

    hipMemsetAsync(h0, 0, HDIM * sizeof(float), stream);

    // Phase 1: xp = x @ Wx^T + Bh   (M=T_SEQ, N=HDIM, K=EDIM)
    gemm_nt_bias<<<dim3(HDIM / 64, T_SEQ / 64), 256, 0, stream>>>(
        x, Wx, Bh, xp, T_SEQ, HDIM, EDIM);

    // Phase 2: recurrence (cooperative, 256 blocks x 512 threads)
    int T = T_SEQ;
    const float* xp_c = xp;
    void* args[] = {(void*)&Wh, (void*)&xp_c, (void*)&h0, (void*)&hs, (void*)&T};
    hipLaunchCooperativeKernel((void*)rnn_recurrence, dim3(HDIM / 8), dim3(512),
                               args, 0, stream);

    // Phase 3: logits = hs @ Wy^T + By   (M=T_SEQ, N=EDIM, K=HDIM)
    gemm_nt_bias<<<dim3(EDIM / 64, T_SEQ / 64), 256, 0, stream>>>(
        hs, Wy, By, logits, T_SEQ, EDIM, HDIM);

    // Phase 4: h_final = hs[T-1] (copy before softmax overwrites hs region)
    copy_vec<<<dim3(HDIM / 256), 256, 0, stream>>>(
        hs + (size_t)(T_SEQ - 1) * HDIM, hfinal, HDIM);

    // Phase 5: softmax rows: logits (ws) -> output region of d_out
    softmax_rows<<<dim3(T_SEQ), 256, 0, stream>>>(logits, hs);
}

// Round 2
// 47293.637 us; speedup vs baseline: 10.9091x; 10.9091x over previous
//
#include <hip/hip_runtime.h>

#define T_SEQ 8192
#define HDIM  2048
#define EDIM  2048
#define NBLK  256   // recurrence grid: one block per CU

// ---------------------------------------------------------------------------
// GEMM (NT): C[m][n] = sum_k A[m][k] * B[n][k] + bias[n]
// A: [M][K] row-major, B: [N][K] row-major. M,N % 64 == 0, K % 32 == 0.
// BM=BN=64, BK=32, 256 threads, 4x4 microtile per thread.
// ---------------------------------------------------------------------------
__global__ __launch_bounds__(256) void gemm_nt_bias(
    const float* __restrict__ A, const float* __restrict__ B,
    const float* __restrict__ bias, float* __restrict__ C,
    int M, int N, int K)
{
    constexpr int BK = 32;
    __shared__ float As[BK][64 + 4];
    __shared__ float Bs[BK][64 + 4];

    const int tx = threadIdx.x & 15;
    const int ty = threadIdx.x >> 4;
    const int m0 = blockIdx.y * 64;
    const int n0 = blockIdx.x * 64;

    float acc[4][4] = {};

    for (int kk = 0; kk < K; kk += BK) {
        #pragma unroll
        for (int p = 0; p < 8; ++p) {
            int idx = p * 256 + threadIdx.x;
            int r = idx >> 5;
            int c = idx & 31;
            As[c][r] = A[(size_t)(m0 + r) * K + kk + c];
            Bs[c][r] = B[(size_t)(n0 + r) * K + kk + c];
        }
        __syncthreads();
        #pragma unroll
        for (int k = 0; k < BK; ++k) {
            float4 a = *(const float4*)&As[k][ty * 4];
            float4 b = *(const float4*)&Bs[k][tx * 4];
            float av[4] = {a.x, a.y, a.z, a.w};
            float bv[4] = {b.x, b.y, b.z, b.w};
            #pragma unroll
            for (int i = 0; i < 4; ++i)
                #pragma unroll
                for (int j = 0; j < 4; ++j)
                    acc[i][j] = fmaf(av[i], bv[j], acc[i][j]);
        }
        __syncthreads();
    }

    float4 bb = *(const float4*)&bias[n0 + tx * 4];
    float bvv[4] = {bb.x, bb.y, bb.z, bb.w};
    #pragma unroll
    for (int i = 0; i < 4; ++i) {
        float4 o;
        o.x = acc[i][0] + bvv[0];
        o.y = acc[i][1] + bvv[1];
        o.z = acc[i][2] + bvv[2];
        o.w = acc[i][3] + bvv[3];
        *(float4*)&C[(size_t)(m0 + ty * 4 + i) * N + n0 + tx * 4] = o;
    }
}

// ---------------------------------------------------------------------------
// Recurrence with custom cross-XCD dataflow sync (no grid.sync, no L2 flush).
//  - 256 blocks x 512 threads; wave w of block b owns row b*8+w; W_h row in
//    32 VGPRs per lane.
//  - h exchanged via double-buffered hbuf[2][HDIM] using AGENT-scope atomics
//    (sc1: write-through / L2-bypass loads -> coherent via L3).
//  - per-block flags[2][NBLK]: flag[p][b] = t  means block b finished step t
//    (parity p = t&1). Readers poll flags, then bulk-load hbuf.
//  - Double buffering is safe: a block writes buffer p for step t+2 only
//    after seeing ALL flags of step t+1, which implies every block finished
//    reading step t from that buffer.
// ---------------------------------------------------------------------------
__global__ __launch_bounds__(512, 1) void rnn_recurrence(
    const float* __restrict__ Wh, const float* __restrict__ xp,
    float* __restrict__ Hs, float* __restrict__ hbuf, int* __restrict__ flags,
    int T)
{
    const int lane = threadIdx.x & 63;
    const int wid  = threadIdx.x >> 6;       // 0..7
    const int row  = blockIdx.x * 8 + wid;   // 0..HDIM-1

    // lane holds W_h[row][t8*256 + lane*4 + e]
    float4 w[8];
    const float4* wrow = (const float4*)(Wh + (size_t)row * HDIM);
    #pragma unroll
    for (int t8 = 0; t8 < 8; ++t8) w[t8] = wrow[t8 * 64 + lane];

    __shared__ float hsm[HDIM];

    for (int t = 0; t < T; ++t) {
        float accv = 0.0f;
        if (t > 0) {
            const int p = t & 1;
            // --- wait for all blocks' step-t flags (64 pollers, 4 flags ea) ---
            if (threadIdx.x < 64) {
                const unsigned long long tgt =
                    (unsigned long long)(unsigned)t | ((unsigned long long)(unsigned)t << 32);
                const unsigned long long* f8 =
                    (const unsigned long long*)&flags[p * NBLK + threadIdx.x * 4];
                while (__hip_atomic_load(&f8[0], __ATOMIC_RELAXED, __HIP_MEMORY_SCOPE_AGENT) != tgt)
                    __builtin_amdgcn_s_sleep(1);
                while (__hip_atomic_load(&f8[1], __ATOMIC_RELAXED, __HIP_MEMORY_SCOPE_AGENT) != tgt)
                    __builtin_amdgcn_s_sleep(1);
            }
            __syncthreads();
            // --- bulk load h_t (16KB as u64) into LDS ---
            const unsigned long long* hb =
                (const unsigned long long*)(hbuf + (size_t)p * HDIM);
            ((unsigned long long*)hsm)[threadIdx.x] =
                __hip_atomic_load(&hb[threadIdx.x], __ATOMIC_RELAXED, __HIP_MEMORY_SCOPE_AGENT);
            ((unsigned long long*)hsm)[threadIdx.x + 512] =
                __hip_atomic_load(&hb[threadIdx.x + 512], __ATOMIC_RELAXED, __HIP_MEMORY_SCOPE_AGENT);
            __syncthreads();
            // --- dot: W_h[row] . h_t  (4 parallel FMA chains) ---
            float ax = 0.f, ay = 0.f, az = 0.f, aw = 0.f;
            #pragma unroll
            for (int t8 = 0; t8 < 8; ++t8) {
                float4 h4 = ((const float4*)hsm)[t8 * 64 + lane];
                ax = fmaf(w[t8].x, h4.x, ax);
                ay = fmaf(w[t8].y, h4.y, ay);
                az = fmaf(w[t8].z, h4.z, az);
                aw = fmaf(w[t8].w, h4.w, aw);
            }
            accv = (ax + ay) + (az + aw);
            #pragma unroll
            for (int off = 32; off > 0; off >>= 1) accv += __shfl_xor(accv, off);
        }

        float z  = accv + xp[(size_t)t * HDIM + row];
        float hn = tanhf(z);

        if (lane == 0) {
            Hs[(size_t)t * HDIM + row] = hn;  // plain store (consumed next dispatch)
            __hip_atomic_store(&hbuf[(size_t)((t + 1) & 1) * HDIM + row], hn,
                               __ATOMIC_RELAXED, __HIP_MEMORY_SCOPE_AGENT);
        }
        __syncthreads();  // drains each wave's vmcnt before barrier
        if (threadIdx.x == 0) {
            asm volatile("s_waitcnt vmcnt(0)" ::: "memory");
            __hip_atomic_store(&flags[((t + 1) & 1) * NBLK + (int)blockIdx.x], t + 1,
                               __ATOMIC_RELAXED, __HIP_MEMORY_SCOPE_AGENT);
        }
    }
}

// ---------------------------------------------------------------------------
// Row softmax over EDIM=2048: one block (256 threads) per row.
// ---------------------------------------------------------------------------
__global__ __launch_bounds__(256) void softmax_rows(
    const float* __restrict__ logits, float* __restrict__ out)
{
    const int row = blockIdx.x;
    const float4* in4 = (const float4*)(logits + (size_t)row * EDIM);
    float4* out4 = (float4*)(out + (size_t)row * EDIM);

    float4 v0 = in4[threadIdx.x];
    float4 v1 = in4[threadIdx.x + 256];

    float m = fmaxf(fmaxf(fmaxf(v0.x, v0.y), fmaxf(v0.z, v0.w)),
                    fmaxf(fmaxf(v1.x, v1.y), fmaxf(v1.z, v1.w)));
    #pragma unroll
    for (int off = 32; off > 0; off >>= 1) m = fmaxf(m, __shfl_xor(m, off));

    __shared__ float red[4];
    if ((threadIdx.x & 63) == 0) red[threadIdx.x >> 6] = m;
    __syncthreads();
    m = fmaxf(fmaxf(red[0], red[1]), fmaxf(red[2], red[3]));
    __syncthreads();

    float e[8];
    e[0] = expf(v0.x - m); e[1] = expf(v0.y - m);
    e[2] = expf(v0.z - m); e[3] = expf(v0.w - m);
    e[4] = expf(v1.x - m); e[5] = expf(v1.y - m);
    e[6] = expf(v1.z - m); e[7] = expf(v1.w - m);

    float s = e[0] + e[1] + e[2] + e[3] + e[4] + e[5] + e[6] + e[7];
    #pragma unroll
    for (int off = 32; off > 0; off >>= 1) s += __shfl_xor(s, off);
    if ((threadIdx.x & 63) == 0) red[threadIdx.x >> 6] = s;
    __syncthreads();
    s = red[0] + red[1] + red[2] + red[3];

    float inv = 1.0f / s;
    out4[threadIdx.x]       = make_float4(e[0] * inv, e[1] * inv, e[2] * inv, e[3] * inv);
    out4[threadIdx.x + 256] = make_float4(e[4] * inv, e[5] * inv, e[6] * inv, e[7] * inv);
}

__global__ void copy_vec(const float* __restrict__ src, float* __restrict__ dst, int n)
{
    int i = blockIdx.x * blockDim.x + threadIdx.x;
    if (i < n) dst[i] = src[i];
}

// ---------------------------------------------------------------------------
extern "C" void kernel_launch(void* const* d_in, const int* in_sizes, int n_in,
                              void* d_out, int out_size, void* d_ws, size_t ws_size,
                              hipStream_t stream)
{
    const float* x  = (const float*)d_in[0];   // [T_SEQ][EDIM]
    const float* Wh = (const float*)d_in[1];   // [HDIM][HDIM]
    const float* Wx = (const float*)d_in[2];   // [HDIM][EDIM]
    const float* Wy = (const float*)d_in[3];   // [EDIM][HDIM]
    const float* Bh = (const float*)d_in[4];   // [HDIM]
    const float* By = (const float*)d_in[5];   // [EDIM]

    float* out    = (float*)d_out;
    float* hfinal = out;                 // [HDIM]
    float* hs     = out + HDIM;          // [T_SEQ][HDIM]: holds hs, then probs

    float* xp     = (float*)d_ws;                                   // [T_SEQ][HDIM]
    char*  sync_base = (char*)d_ws + (size_t)T_SEQ * HDIM * 4;
    float* hbuf   = (float*)sync_base;                              // [2][HDIM]
    int*   flags  = (int*)(sync_base + 2 * HDIM * sizeof(float));   // [2][NBLK]
    float* logits = xp;                  // reuse (xp dead after recurrence)

    // clear sync state (flags + h buffers) so replays never see stale tags
    hipMemsetAsync(sync_base, 0, 2 * HDIM * sizeof(float) + 2 * NBLK * sizeof(int),
                   stream);

    // Phase 1: xp = x @ Wx^T + Bh
    gemm_nt_bias<<<dim3(HDIM / 64, T_SEQ / 64), 256, 0, stream>>>(
        x, Wx, Bh, xp, T_SEQ, HDIM, EDIM);

    // Phase 2: recurrence — cooperative launch only to guarantee co-residency
    int T = T_SEQ;
    const float* xp_c = xp;
    void* args[] = {(void*)&Wh, (void*)&xp_c, (void*)&hs, (void*)&hbuf,
                    (void*)&flags, (void*)&T};
    hipLaunchCooperativeKernel((void*)rnn_recurrence, dim3(NBLK), dim3(512),
                               args, 0, stream);

    // Phase 3: logits = hs @ Wy^T + By
    gemm_nt_bias<<<dim3(EDIM / 64, T_SEQ / 64), 256, 0, stream>>>(
        hs, Wy, By, logits, T_SEQ, EDIM, HDIM);

    // Phase 4: h_final = hs[T-1] (before softmax overwrites hs region)
    copy_vec<<<dim3(HDIM / 256), 256, 0, stream>>>(
        hs + (size_t)(T_SEQ - 1) * HDIM, hfinal, HDIM);

    // Phase 5: softmax rows: logits (ws) -> output region of d_out
    softmax_rows<<<dim3(T_SEQ), 256, 0, stream>>>(logits, hs);
}

// Round 3
// 37577.490 us; speedup vs baseline: 13.7298x; 1.2586x over previous
//
#include <hip/hip_runtime.h>

#define T_SEQ 8192
#define HDIM  2048
#define EDIM  2048
#define NBLK  256   // recurrence grid: one block per CU

typedef unsigned long long u64;

// ---------------------------------------------------------------------------
// GEMM (NT): C[m][n] = sum_k A[m][k] * B[n][k] + bias[n]
// ---------------------------------------------------------------------------
__global__ __launch_bounds__(256) void gemm_nt_bias(
    const float* __restrict__ A, const float* __restrict__ B,
    const float* __restrict__ bias, float* __restrict__ C,
    int M, int N, int K)
{
    constexpr int BK = 32;
    __shared__ float As[BK][64 + 4];
    __shared__ float Bs[BK][64 + 4];

    const int tx = threadIdx.x & 15;
    const int ty = threadIdx.x >> 4;
    const int m0 = blockIdx.y * 64;
    const int n0 = blockIdx.x * 64;

    float acc[4][4] = {};

    for (int kk = 0; kk < K; kk += BK) {
        #pragma unroll
        for (int p = 0; p < 8; ++p) {
            int idx = p * 256 + threadIdx.x;
            int r = idx >> 5;
            int c = idx & 31;
            As[c][r] = A[(size_t)(m0 + r) * K + kk + c];
            Bs[c][r] = B[(size_t)(n0 + r) * K + kk + c];
        }
        __syncthreads();
        #pragma unroll
        for (int k = 0; k < BK; ++k) {
            float4 a = *(const float4*)&As[k][ty * 4];
            float4 b = *(const float4*)&Bs[k][tx * 4];
            float av[4] = {a.x, a.y, a.z, a.w};
            float bv[4] = {b.x, b.y, b.z, b.w};
            #pragma unroll
            for (int i = 0; i < 4; ++i)
                #pragma unroll
                for (int j = 0; j < 4; ++j)
                    acc[i][j] = fmaf(av[i], bv[j], acc[i][j]);
        }
        __syncthreads();
    }

    float4 bb = *(const float4*)&bias[n0 + tx * 4];
    float bvv[4] = {bb.x, bb.y, bb.z, bb.w};
    #pragma unroll
    for (int i = 0; i < 4; ++i) {
        float4 o;
        o.x = acc[i][0] + bvv[0];
        o.y = acc[i][1] + bvv[1];
        o.z = acc[i][2] + bvv[2];
        o.w = acc[i][3] + bvv[3];
        *(float4*)&C[(size_t)(m0 + ty * 4 + i) * N + n0 + tx * 4] = o;
    }
}

// ---------------------------------------------------------------------------
// Recurrence with single-hop tagged-word dataflow sync.
//   hbuf[2][HDIM] of u64: (tag<<32)|f32bits(h). Step t's output h_{t+1} is
//   written with tag t+1 into buffer (t+1)&1. Readers of step t poll the 2048
//   words of buffer t&1 until every tag == t (each thread owns 4 words),
//   then stage payloads into LDS. No fences/flags: the tag travels with the
//   data (8B aligned stores are single-copy atomic). Overwrite of the
//   recycled buffer is safe because a writer's tag-t store arithmetically
//   depends on all its step-(t-1) loads having completed.
// ---------------------------------------------------------------------------
__global__ __launch_bounds__(512, 1) void rnn_recurrence(
    const float* __restrict__ Wh, const float* __restrict__ xp,
    float* __restrict__ Hs, u64* __restrict__ hbuf, int T)
{
    const int lane = threadIdx.x & 63;
    const int wid  = threadIdx.x >> 6;       // 0..7
    const int row  = blockIdx.x * 8 + wid;   // 0..HDIM-1

    // lane holds W_h[row][t8*256 + lane*4 + e]
    float4 w[8];
    const float4* wrow = (const float4*)(Wh + (size_t)row * HDIM);
    #pragma unroll
    for (int t8 = 0; t8 < 8; ++t8) w[t8] = wrow[t8 * 64 + lane];

    __shared__ float hsm[HDIM];
    const int i0 = threadIdx.x;

    for (int t = 0; t < T; ++t) {
        // prefetch xp for THIS step before any poll -> latency hides under wait
        float xq = xp[(size_t)t * HDIM + row];

        float accv = 0.0f;
        if (t > 0) {
            const u64* hb = hbuf + (size_t)(t & 1) * HDIM;
            const unsigned tg = (unsigned)t;

            u64 v0 = __hip_atomic_load(&hb[i0],        __ATOMIC_RELAXED, __HIP_MEMORY_SCOPE_AGENT);
            u64 v1 = __hip_atomic_load(&hb[i0 +  512], __ATOMIC_RELAXED, __HIP_MEMORY_SCOPE_AGENT);
            u64 v2 = __hip_atomic_load(&hb[i0 + 1024], __ATOMIC_RELAXED, __HIP_MEMORY_SCOPE_AGENT);
            u64 v3 = __hip_atomic_load(&hb[i0 + 1536], __ATOMIC_RELAXED, __HIP_MEMORY_SCOPE_AGENT);
            while ((unsigned)(v0 >> 32) != tg)
                v0 = __hip_atomic_load(&hb[i0],        __ATOMIC_RELAXED, __HIP_MEMORY_SCOPE_AGENT);
            while ((unsigned)(v1 >> 32) != tg)
                v1 = __hip_atomic_load(&hb[i0 +  512], __ATOMIC_RELAXED, __HIP_MEMORY_SCOPE_AGENT);
            while ((unsigned)(v2 >> 32) != tg)
                v2 = __hip_atomic_load(&hb[i0 + 1024], __ATOMIC_RELAXED, __HIP_MEMORY_SCOPE_AGENT);
            while ((unsigned)(v3 >> 32) != tg)
                v3 = __hip_atomic_load(&hb[i0 + 1536], __ATOMIC_RELAXED, __HIP_MEMORY_SCOPE_AGENT);

            hsm[i0]        = __uint_as_float((unsigned)v0);
            hsm[i0 +  512] = __uint_as_float((unsigned)v1);
            hsm[i0 + 1024] = __uint_as_float((unsigned)v2);
            hsm[i0 + 1536] = __uint_as_float((unsigned)v3);
            __syncthreads();

            // dot: W_h[row] . h_t  (4 parallel FMA chains)
            float ax = 0.f, ay = 0.f, az = 0.f, aw = 0.f;
            #pragma unroll
            for (int t8 = 0; t8 < 8; ++t8) {
                float4 h4 = ((const float4*)hsm)[t8 * 64 + lane];
                ax = fmaf(w[t8].x, h4.x, ax);
                ay = fmaf(w[t8].y, h4.y, ay);
                az = fmaf(w[t8].z, h4.z, az);
                aw = fmaf(w[t8].w, h4.w, aw);
            }
            accv = (ax + ay) + (az + aw);
            #pragma unroll
            for (int off = 32; off > 0; off >>= 1) accv += __shfl_xor(accv, off);
        }

        float z  = accv + xq;
        float hn = tanhf(z);

        if (lane == 0) {
            Hs[(size_t)t * HDIM + row] = hn;   // plain store, consumed next dispatch
            u64 pk = ((u64)(unsigned)(t + 1) << 32) | (u64)__float_as_uint(hn);
            __hip_atomic_store(&hbuf[(size_t)((t + 1) & 1) * HDIM + row], pk,
                               __ATOMIC_RELAXED, __HIP_MEMORY_SCOPE_AGENT);
        }
        // no barrier needed: next iteration's hsm overwrite is gated by the
        // poll, which requires every wave's tagged store (which data-depends
        // on that wave's reads of hsm) to be visible.
    }
}

// ---------------------------------------------------------------------------
// Row softmax over EDIM=2048: one block (256 threads) per row.
// ---------------------------------------------------------------------------
__global__ __launch_bounds__(256) void softmax_rows(
    const float* __restrict__ logits, float* __restrict__ out)
{
    const int row = blockIdx.x;
    const float4* in4 = (const float4*)(logits + (size_t)row * EDIM);
    float4* out4 = (float4*)(out + (size_t)row * EDIM);

    float4 v0 = in4[threadIdx.x];
    float4 v1 = in4[threadIdx.x + 256];

    float m = fmaxf(fmaxf(fmaxf(v0.x, v0.y), fmaxf(v0.z, v0.w)),
                    fmaxf(fmaxf(v1.x, v1.y), fmaxf(v1.z, v1.w)));
    #pragma unroll
    for (int off = 32; off > 0; off >>= 1) m = fmaxf(m, __shfl_xor(m, off));

    __shared__ float red[4];
    if ((threadIdx.x & 63) == 0) red[threadIdx.x >> 6] = m;
    __syncthreads();
    m = fmaxf(fmaxf(red[0], red[1]), fmaxf(red[2], red[3]));
    __syncthreads();

    float e[8];
    e[0] = expf(v0.x - m); e[1] = expf(v0.y - m);
    e[2] = expf(v0.z - m); e[3] = expf(v0.w - m);
    e[4] = expf(v1.x - m); e[5] = expf(v1.y - m);
    e[6] = expf(v1.z - m); e[7] = expf(v1.w - m);

    float s = e[0] + e[1] + e[2] + e[3] + e[4] + e[5] + e[6] + e[7];
    #pragma unroll
    for (int off = 32; off > 0; off >>= 1) s += __shfl_xor(s, off);
    if ((threadIdx.x & 63) == 0) red[threadIdx.x >> 6] = s;
    __syncthreads();
    s = red[0] + red[1] + red[2] + red[3];

    float inv = 1.0f / s;
    out4[threadIdx.x]       = make_float4(e[0] * inv, e[1] * inv, e[2] * inv, e[3] * inv);
    out4[threadIdx.x + 256] = make_float4(e[4] * inv, e[5] * inv, e[6] * inv, e[7] * inv);
}

__global__ void copy_vec(const float* __restrict__ src, float* __restrict__ dst, int n)
{
    int i = blockIdx.x * blockDim.x + threadIdx.x;
    if (i < n) dst[i] = src[i];
}

// ---------------------------------------------------------------------------
extern "C" void kernel_launch(void* const* d_in, const int* in_sizes, int n_in,
                              void* d_out, int out_size, void* d_ws, size_t ws_size,
                              hipStream_t stream)
{
    const float* x  = (const float*)d_in[0];   // [T_SEQ][EDIM]
    const float* Wh = (const float*)d_in[1];   // [HDIM][HDIM]
    const float* Wx = (const float*)d_in[2];   // [HDIM][EDIM]
    const float* Wy = (const float*)d_in[3];   // [EDIM][HDIM]
    const float* Bh = (const float*)d_in[4];   // [HDIM]
    const float* By = (const float*)d_in[5];   // [EDIM]

    float* out    = (float*)d_out;
    float* hfinal = out;                 // [HDIM]
    float* hs     = out + HDIM;          // [T_SEQ][HDIM]: holds hs, then probs

    float* xp   = (float*)d_ws;                                   // [T_SEQ][HDIM]
    u64*   hbuf = (u64*)((char*)d_ws + (size_t)T_SEQ * HDIM * 4); // [2][HDIM]
    float* logits = xp;                  // reuse (xp dead after recurrence)

    // clear tagged h buffers so replays never see stale tags
    hipMemsetAsync(hbuf, 0, 2 * HDIM * sizeof(u64), stream);

    // Phase 1: xp = x @ Wx^T + Bh
    gemm_nt_bias<<<dim3(HDIM / 64, T_SEQ / 64), 256, 0, stream>>>(
        x, Wx, Bh, xp, T_SEQ, HDIM, EDIM);

    // Phase 2: recurrence — cooperative launch only to guarantee co-residency
    int T = T_SEQ;
    const float* xp_c = xp;
    void* args[] = {(void*)&Wh, (void*)&xp_c, (void*)&hs, (void*)&hbuf, (void*)&T};
    hipLaunchCooperativeKernel((void*)rnn_recurrence, dim3(NBLK), dim3(512),
                               args, 0, stream);

    // Phase 3: logits = hs @ Wy^T + By
    gemm_nt_bias<<<dim3(EDIM / 64, T_SEQ / 64), 256, 0, stream>>>(
        hs, Wy, By, logits, T_SEQ, EDIM, HDIM);

    // Phase 4: h_final = hs[T-1] (before softmax overwrites hs region)
    copy_vec<<<dim3(HDIM / 256), 256, 0, stream>>>(
        hs + (size_t)(T_SEQ - 1) * HDIM, hfinal, HDIM);

    // Phase 5: softmax rows: logits (ws) -> output region of d_out
    softmax_rows<<<dim3(T_SEQ), 256, 0, stream>>>(logits, hs);
}

// Round 4
// 18466.969 us; speedup vs baseline: 27.9382x; 2.0348x over previous
//
#include <hip/hip_runtime.h>

#define T_SEQ 8192
#define HDIM  2048
#define EDIM  2048
#define RBLK  64                      // recurrence blocks (fabric fan-out = RBLK*16KB/step)
#define ROWS_PER_BLK (HDIM / RBLK)    // 32 rows/block, 4 rows/wave

typedef unsigned long long u64;
typedef __attribute__((ext_vector_type(4))) unsigned int u32x4;

// 16B agent-coherent load (bypasses L1+L2, serviced at fabric/L3)
__device__ inline u32x4 poll_one(const u64* p) {
    u32x4 a;
    asm volatile("global_load_dwordx4 %0, %1, off sc1\n\ts_waitcnt vmcnt(0)"
                 : "=v"(a) : "v"(p) : "memory");
    return a;
}
__device__ inline void poll_pair(const u64* p0, const u64* p1, u32x4& a, u32x4& b) {
    asm volatile("global_load_dwordx4 %0, %2, off sc1\n\t"
                 "global_load_dwordx4 %1, %3, off sc1\n\t"
                 "s_waitcnt vmcnt(0)"
                 : "=v"(a), "=v"(b) : "v"(p0), "v"(p1) : "memory");
}

// ---------------------------------------------------------------------------
// GEMM (NT): C[m][n] = sum_k A[m][k] * B[n][k] + bias[n]
// ---------------------------------------------------------------------------
__global__ __launch_bounds__(256) void gemm_nt_bias(
    const float* __restrict__ A, const float* __restrict__ B,
    const float* __restrict__ bias, float* __restrict__ C,
    int M, int N, int K)
{
    constexpr int BK = 32;
    __shared__ float As[BK][64 + 4];
    __shared__ float Bs[BK][64 + 4];

    const int tx = threadIdx.x & 15;
    const int ty = threadIdx.x >> 4;
    const int m0 = blockIdx.y * 64;
    const int n0 = blockIdx.x * 64;

    float acc[4][4] = {};

    for (int kk = 0; kk < K; kk += BK) {
        #pragma unroll
        for (int p = 0; p < 8; ++p) {
            int idx = p * 256 + threadIdx.x;
            int r = idx >> 5;
            int c = idx & 31;
            As[c][r] = A[(size_t)(m0 + r) * K + kk + c];
            Bs[c][r] = B[(size_t)(n0 + r) * K + kk + c];
        }
        __syncthreads();
        #pragma unroll
        for (int k = 0; k < BK; ++k) {
            float4 a = *(const float4*)&As[k][ty * 4];
            float4 b = *(const float4*)&Bs[k][tx * 4];
            float av[4] = {a.x, a.y, a.z, a.w};
            float bv[4] = {b.x, b.y, b.z, b.w};
            #pragma unroll
            for (int i = 0; i < 4; ++i)
                #pragma unroll
                for (int j = 0; j < 4; ++j)
                    acc[i][j] = fmaf(av[i], bv[j], acc[i][j]);
        }
        __syncthreads();
    }

    float4 bb = *(const float4*)&bias[n0 + tx * 4];
    float bvv[4] = {bb.x, bb.y, bb.z, bb.w};
    #pragma unroll
    for (int i = 0; i < 4; ++i) {
        float4 o;
        o.x = acc[i][0] + bvv[0];
        o.y = acc[i][1] + bvv[1];
        o.z = acc[i][2] + bvv[2];
        o.w = acc[i][3] + bvv[3];
        *(float4*)&C[(size_t)(m0 + ty * 4 + i) * N + n0 + tx * 4] = o;
    }
}

// ---------------------------------------------------------------------------
// Recurrence, 64 blocks x 512 threads. Wave w of block b owns rows
// b*32 + w*4 .. +3, with W_h held in 128 VGPRs/lane (4 rows x 8 float4;
// lane holds W[row][t8*256 + lane*4 + e]).
//
// Sync: hbuf[2][HDIM] of u64 (tag<<32 | f32bits). Step t's writers store
// tag t+1 into buffer (t+1)&1 (8B relaxed agent atomics — tag travels with
// data, no fence). Readers poll 16B dwordx4 sc1 loads (2 tagged words per
// request, per-u64 tag check), stage payloads to LDS, dot, 4 xor-reductions,
// lanes 0-3 store one row each. Overwrite of the recycled buffer is safe:
// a wave's tag-t store value-depends on ALL its step-(t-1) loads, and a
// poll success requires all 2048 tag-t words.
// ---------------------------------------------------------------------------
__global__ __launch_bounds__(512, 2) void rnn_recurrence(
    const float* __restrict__ Wh, const float* __restrict__ xp,
    float* __restrict__ Hs, u64* __restrict__ hbuf, int T)
{
    const int tid  = threadIdx.x;
    const int lane = tid & 63;
    const int wid  = tid >> 6;                              // 0..7
    const int r0   = blockIdx.x * ROWS_PER_BLK + wid * 4;   // wave's first row

    float4 w[4][8];
    #pragma unroll
    for (int r = 0; r < 4; ++r) {
        const float4* wrow = (const float4*)(Wh + (size_t)(r0 + r) * HDIM);
        #pragma unroll
        for (int t8 = 0; t8 < 8; ++t8) w[r][t8] = wrow[t8 * 64 + lane];
    }

    __shared__ float hsm[HDIM];

    for (int t = 0; t < T; ++t) {
        // prefetch this step's xp before any poll (latency hides under wait)
        float xq = 0.f;
        if (lane < 4) xq = xp[(size_t)t * HDIM + r0 + lane];

        float s0 = 0.f, s1 = 0.f, s2 = 0.f, s3 = 0.f;
        if (t > 0) {
            const u64* hb = hbuf + (size_t)(t & 1) * HDIM;
            const unsigned tg = (unsigned)t;
            const u64* p0 = hb + 2 * tid;          // rows 2*tid, 2*tid+1
            const u64* p1 = hb + 1024 + 2 * tid;   // rows 1024+2*tid, +1

            u32x4 a, b;
            poll_pair(p0, p1, a, b);
            while (a.y != tg || a.w != tg) a = poll_one(p0);
            while (b.y != tg || b.w != tg) b = poll_one(p1);

            ((float2*)hsm)[tid] =
                make_float2(__uint_as_float(a.x), __uint_as_float(a.z));
            ((float2*)hsm)[tid + 512] =
                make_float2(__uint_as_float(b.x), __uint_as_float(b.z));
            __syncthreads();

            #pragma unroll
            for (int t8 = 0; t8 < 8; ++t8) {
                float4 h4 = ((const float4*)hsm)[t8 * 64 + lane];
                s0 = fmaf(w[0][t8].x, h4.x, s0); s0 = fmaf(w[0][t8].y, h4.y, s0);
                s0 = fmaf(w[0][t8].z, h4.z, s0); s0 = fmaf(w[0][t8].w, h4.w, s0);
                s1 = fmaf(w[1][t8].x, h4.x, s1); s1 = fmaf(w[1][t8].y, h4.y, s1);
                s1 = fmaf(w[1][t8].z, h4.z, s1); s1 = fmaf(w[1][t8].w, h4.w, s1);
                s2 = fmaf(w[2][t8].x, h4.x, s2); s2 = fmaf(w[2][t8].y, h4.y, s2);
                s2 = fmaf(w[2][t8].z, h4.z, s2); s2 = fmaf(w[2][t8].w, h4.w, s2);
                s3 = fmaf(w[3][t8].x, h4.x, s3); s3 = fmaf(w[3][t8].y, h4.y, s3);
                s3 = fmaf(w[3][t8].z, h4.z, s3); s3 = fmaf(w[3][t8].w, h4.w, s3);
            }
            #pragma unroll
            for (int off = 32; off > 0; off >>= 1) {
                s0 += __shfl_xor(s0, off);
                s1 += __shfl_xor(s1, off);
                s2 += __shfl_xor(s2, off);
                s3 += __shfl_xor(s3, off);
            }
            // no trailing barrier: next-step hsm writes are gated by the poll,
            // which requires every wave's value-dependent tagged store.
        }

        if (lane < 4) {
            float sv = (lane == 0) ? s0 : (lane == 1) ? s1 : (lane == 2) ? s2 : s3;
            float hn = tanhf(sv + xq);
            Hs[(size_t)t * HDIM + r0 + lane] = hn;   // consumed by next dispatch
            u64 pk = ((u64)(unsigned)(t + 1) << 32) | (u64)__float_as_uint(hn);
            __hip_atomic_store(&hbuf[(size_t)((t + 1) & 1) * HDIM + r0 + lane], pk,
                               __ATOMIC_RELAXED, __HIP_MEMORY_SCOPE_AGENT);
        }
    }
}

// ---------------------------------------------------------------------------
// Row softmax over EDIM=2048: one block (256 threads) per row.
// ---------------------------------------------------------------------------
__global__ __launch_bounds__(256) void softmax_rows(
    const float* __restrict__ logits, float* __restrict__ out)
{
    const int row = blockIdx.x;
    const float4* in4 = (const float4*)(logits + (size_t)row * EDIM);
    float4* out4 = (float4*)(out + (size_t)row * EDIM);

    float4 v0 = in4[threadIdx.x];
    float4 v1 = in4[threadIdx.x + 256];

    float m = fmaxf(fmaxf(fmaxf(v0.x, v0.y), fmaxf(v0.z, v0.w)),
                    fmaxf(fmaxf(v1.x, v1.y), fmaxf(v1.z, v1.w)));
    #pragma unroll
    for (int off = 32; off > 0; off >>= 1) m = fmaxf(m, __shfl_xor(m, off));

    __shared__ float red[4];
    if ((threadIdx.x & 63) == 0) red[threadIdx.x >> 6] = m;
    __syncthreads();
    m = fmaxf(fmaxf(red[0], red[1]), fmaxf(red[2], red[3]));
    __syncthreads();

    float e[8];
    e[0] = expf(v0.x - m); e[1] = expf(v0.y - m);
    e[2] = expf(v0.z - m); e[3] = expf(v0.w - m);
    e[4] = expf(v1.x - m); e[5] = expf(v1.y - m);
    e[6] = expf(v1.z - m); e[7] = expf(v1.w - m);

    float s = e[0] + e[1] + e[2] + e[3] + e[4] + e[5] + e[6] + e[7];
    #pragma unroll
    for (int off = 32; off > 0; off >>= 1) s += __shfl_xor(s, off);
    if ((threadIdx.x & 63) == 0) red[threadIdx.x >> 6] = s;
    __syncthreads();
    s = red[0] + red[1] + red[2] + red[3];

    float inv = 1.0f / s;
    out4[threadIdx.x]       = make_float4(e[0] * inv, e[1] * inv, e[2] * inv, e[3] * inv);
    out4[threadIdx.x + 256] = make_float4(e[4] * inv, e[5] * inv, e[6] * inv, e[7] * inv);
}

__global__ void copy_vec(const float* __restrict__ src, float* __restrict__ dst, int n)
{
    int i = blockIdx.x * blockDim.x + threadIdx.x;
    if (i < n) dst[i] = src[i];
}

// ---------------------------------------------------------------------------
extern "C" void kernel_launch(void* const* d_in, const int* in_sizes, int n_in,
                              void* d_out, int out_size, void* d_ws, size_t ws_size,
                              hipStream_t stream)
{
    const float* x  = (const float*)d_in[0];   // [T_SEQ][EDIM]
    const float* Wh = (const float*)d_in[1];   // [HDIM][HDIM]
    const float* Wx = (const float*)d_in[2];   // [HDIM][EDIM]
    const float* Wy = (const float*)d_in[3];   // [EDIM][HDIM]
    const float* Bh = (const float*)d_in[4];   // [HDIM]
    const float* By = (const float*)d_in[5];   // [EDIM]

    float* out    = (float*)d_out;
    float* hfinal = out;                 // [HDIM]
    float* hs     = out + HDIM;          // [T_SEQ][HDIM]: holds hs, then probs

    float* xp   = (float*)d_ws;                                   // [T_SEQ][HDIM]
    u64*   hbuf = (u64*)((char*)d_ws + (size_t)T_SEQ * HDIM * 4); // [2][HDIM]
    float* logits = xp;                  // reuse (xp dead after recurrence)

    // clear tagged h buffers so replays never see stale tags
    hipMemsetAsync(hbuf, 0, 2 * HDIM * sizeof(u64), stream);

    // Phase 1: xp = x @ Wx^T + Bh
    gemm_nt_bias<<<dim3(HDIM / 64, T_SEQ / 64), 256, 0, stream>>>(
        x, Wx, Bh, xp, T_SEQ, HDIM, EDIM);

    // Phase 2: recurrence — cooperative launch only to guarantee co-residency
    int T = T_SEQ;
    const float* xp_c = xp;
    void* args[] = {(void*)&Wh, (void*)&xp_c, (void*)&hs, (void*)&hbuf, (void*)&T};
    hipLaunchCooperativeKernel((void*)rnn_recurrence, dim3(RBLK), dim3(512),
                               args, 0, stream);

    // Phase 3: logits = hs @ Wy^T + By
    gemm_nt_bias<<<dim3(EDIM / 64, T_SEQ / 64), 256, 0, stream>>>(
        hs, Wy, By, logits, T_SEQ, EDIM, HDIM);

    // Phase 4: h_final = hs[T-1] (before softmax overwrites hs region)
    copy_vec<<<dim3(HDIM / 256), 256, 0, stream>>>(
        hs + (size_t)(T_SEQ - 1) * HDIM, hfinal, HDIM);

    // Phase 5: softmax rows: logits (ws) -> output region of d_out
    softmax_rows<<<dim3(T_SEQ), 256, 0, stream>>>(logits, hs);
}

// Round 5
// 17836.212 us; speedup vs baseline: 28.9262x; 1.0354x over previous
//
#include <hip/hip_runtime.h>

#define T_SEQ 8192
#define HDIM  2048
#define EDIM  2048
#define RBLK  64                      // recurrence blocks
#define ROWS_PER_BLK (HDIM / RBLK)    // 32 rows/block, 4 rows/wave

typedef unsigned long long u64;
typedef __attribute__((ext_vector_type(4))) unsigned int u32x4;

// 16B agent-coherent loads (bypass L1/L2, serviced at fabric/L3)
__device__ inline void poll_pair(const u64* p0, const u64* p1, u32x4& a, u32x4& b) {
    asm volatile("global_load_dwordx4 %0, %2, off sc1\n\t"
                 "global_load_dwordx4 %1, %3, off sc1\n\t"
                 "s_waitcnt vmcnt(0)"
                 : "=v"(a), "=v"(b) : "v"(p0), "v"(p1) : "memory");
}

// ---------------------------------------------------------------------------
// GEMM (NT): C[m][n] = sum_k A[m][k] * B[n][k] + bias[n]
// ---------------------------------------------------------------------------
__global__ __launch_bounds__(256) void gemm_nt_bias(
    const float* __restrict__ A, const float* __restrict__ B,
    const float* __restrict__ bias, float* __restrict__ C,
    int M, int N, int K)
{
    constexpr int BK = 32;
    __shared__ float As[BK][64 + 4];
    __shared__ float Bs[BK][64 + 4];

    const int tx = threadIdx.x & 15;
    const int ty = threadIdx.x >> 4;
    const int m0 = blockIdx.y * 64;
    const int n0 = blockIdx.x * 64;

    float acc[4][4] = {};

    for (int kk = 0; kk < K; kk += BK) {
        #pragma unroll
        for (int p = 0; p < 8; ++p) {
            int idx = p * 256 + threadIdx.x;
            int r = idx >> 5;
            int c = idx & 31;
            As[c][r] = A[(size_t)(m0 + r) * K + kk + c];
            Bs[c][r] = B[(size_t)(n0 + r) * K + kk + c];
        }
        __syncthreads();
        #pragma unroll
        for (int k = 0; k < BK; ++k) {
            float4 a = *(const float4*)&As[k][ty * 4];
            float4 b = *(const float4*)&Bs[k][tx * 4];
            float av[4] = {a.x, a.y, a.z, a.w};
            float bv[4] = {b.x, b.y, b.z, b.w};
            #pragma unroll
            for (int i = 0; i < 4; ++i)
                #pragma unroll
                for (int j = 0; j < 4; ++j)
                    acc[i][j] = fmaf(av[i], bv[j], acc[i][j]);
        }
        __syncthreads();
    }

    float4 bb = *(const float4*)&bias[n0 + tx * 4];
    float bvv[4] = {bb.x, bb.y, bb.z, bb.w};
    #pragma unroll
    for (int i = 0; i < 4; ++i) {
        float4 o;
        o.x = acc[i][0] + bvv[0];
        o.y = acc[i][1] + bvv[1];
        o.z = acc[i][2] + bvv[2];
        o.w = acc[i][3] + bvv[3];
        *(float4*)&C[(size_t)(m0 + ty * 4 + i) * N + n0 + tx * 4] = o;
    }
}

// ---------------------------------------------------------------------------
// Recurrence, 64 blocks x 512 threads. Wave w of block b owns rows
// b*32 + w*4 .. +3. W_h held in 32 NAMED float4 (128 VGPRs/lane) so the
// compiler cannot demote it to per-step reloads (R4 bug: VGPR_Count=84).
//
// Sync: hbuf[2][HDIM] of u64 (tag<<32 | f32bits). Tag travels with data
// (8B relaxed agent atomics). Readers poll 16B sc1 loads (2 tagged words
// per request), combined re-poll of both halves. Overwrite of the recycled
// buffer is safe: a wave's tag-t store value-depends on ALL its step-(t-1)
// loads, and poll success requires all 2048 tag-t words.
// ---------------------------------------------------------------------------
__global__ __launch_bounds__(512, 1) void rnn_recurrence(
    const float* __restrict__ Wh, const float* __restrict__ xp,
    float* __restrict__ Hs, u64* __restrict__ hbuf, int T)
{
    const int tid  = threadIdx.x;
    const int lane = tid & 63;
    const int wid  = tid >> 6;                              // 0..7
    const int r0   = blockIdx.x * ROWS_PER_BLK + wid * 4;   // wave's first row

    const float4* wr0 = (const float4*)(Wh + (size_t)(r0 + 0) * HDIM);
    const float4* wr1 = (const float4*)(Wh + (size_t)(r0 + 1) * HDIM);
    const float4* wr2 = (const float4*)(Wh + (size_t)(r0 + 2) * HDIM);
    const float4* wr3 = (const float4*)(Wh + (size_t)(r0 + 3) * HDIM);

    // 32 named float4 = 128 VGPRs of W_h, register-resident for the whole loop
    float4 w00 = wr0[0*64+lane], w01 = wr0[1*64+lane], w02 = wr0[2*64+lane], w03 = wr0[3*64+lane];
    float4 w04 = wr0[4*64+lane], w05 = wr0[5*64+lane], w06 = wr0[6*64+lane], w07 = wr0[7*64+lane];
    float4 w10 = wr1[0*64+lane], w11 = wr1[1*64+lane], w12 = wr1[2*64+lane], w13 = wr1[3*64+lane];
    float4 w14 = wr1[4*64+lane], w15 = wr1[5*64+lane], w16 = wr1[6*64+lane], w17 = wr1[7*64+lane];
    float4 w20 = wr2[0*64+lane], w21 = wr2[1*64+lane], w22 = wr2[2*64+lane], w23 = wr2[3*64+lane];
    float4 w24 = wr2[4*64+lane], w25 = wr2[5*64+lane], w26 = wr2[6*64+lane], w27 = wr2[7*64+lane];
    float4 w30 = wr3[0*64+lane], w31 = wr3[1*64+lane], w32 = wr3[2*64+lane], w33 = wr3[3*64+lane];
    float4 w34 = wr3[4*64+lane], w35 = wr3[5*64+lane], w36 = wr3[6*64+lane], w37 = wr3[7*64+lane];

    __shared__ float hsm[HDIM];

    for (int t = 0; t < T; ++t) {
        // prefetch this step's xp before any poll (latency hides under wait)
        float xq = 0.f;
        if (lane < 4) xq = xp[(size_t)t * HDIM + r0 + lane];

        float s0 = 0.f, s1 = 0.f, s2 = 0.f, s3 = 0.f;
        if (t > 0) {
            const u64* hb = hbuf + (size_t)(t & 1) * HDIM;
            const unsigned tg = (unsigned)t;
            const u64* p0 = hb + 2 * tid;          // rows 2*tid, 2*tid+1
            const u64* p1 = hb + 1024 + 2 * tid;   // rows 1024+2*tid, +1

            u32x4 a, b;
            poll_pair(p0, p1, a, b);
            while ((a.y != tg) | (a.w != tg) | (b.y != tg) | (b.w != tg))
                poll_pair(p0, p1, a, b);           // one latency per round

            ((float2*)hsm)[tid] =
                make_float2(__uint_as_float(a.x), __uint_as_float(a.z));
            ((float2*)hsm)[tid + 512] =
                make_float2(__uint_as_float(b.x), __uint_as_float(b.z));
            __syncthreads();

            #define RNN_STEP(IDX, WA, WB, WC, WD)                                   \
            {   float4 h4 = ((const float4*)hsm)[(IDX) * 64 + lane];                \
                s0 = fmaf(WA.x, h4.x, s0); s0 = fmaf(WA.y, h4.y, s0);               \
                s0 = fmaf(WA.z, h4.z, s0); s0 = fmaf(WA.w, h4.w, s0);               \
                s1 = fmaf(WB.x, h4.x, s1); s1 = fmaf(WB.y, h4.y, s1);               \
                s1 = fmaf(WB.z, h4.z, s1); s1 = fmaf(WB.w, h4.w, s1);               \
                s2 = fmaf(WC.x, h4.x, s2); s2 = fmaf(WC.y, h4.y, s2);               \
                s2 = fmaf(WC.z, h4.z, s2); s2 = fmaf(WC.w, h4.w, s2);               \
                s3 = fmaf(WD.x, h4.x, s3); s3 = fmaf(WD.y, h4.y, s3);               \
                s3 = fmaf(WD.z, h4.z, s3); s3 = fmaf(WD.w, h4.w, s3); }
            RNN_STEP(0, w00, w10, w20, w30)
            RNN_STEP(1, w01, w11, w21, w31)
            RNN_STEP(2, w02, w12, w22, w32)
            RNN_STEP(3, w03, w13, w23, w33)
            RNN_STEP(4, w04, w14, w24, w34)
            RNN_STEP(5, w05, w15, w25, w35)
            RNN_STEP(6, w06, w16, w26, w36)
            RNN_STEP(7, w07, w17, w27, w37)
            #undef RNN_STEP

            #pragma unroll
            for (int off = 32; off > 0; off >>= 1) {
                s0 += __shfl_xor(s0, off);
                s1 += __shfl_xor(s1, off);
                s2 += __shfl_xor(s2, off);
                s3 += __shfl_xor(s3, off);
            }
            // no trailing barrier: next-step hsm writes are gated by the poll.
        }

        if (lane < 4) {
            float sv = (lane == 0) ? s0 : (lane == 1) ? s1 : (lane == 2) ? s2 : s3;
            float hn = tanhf(sv + xq);
            // tagged store FIRST (critical path), Hs store after
            u64 pk = ((u64)(unsigned)(t + 1) << 32) | (u64)__float_as_uint(hn);
            __hip_atomic_store(&hbuf[(size_t)((t + 1) & 1) * HDIM + r0 + lane], pk,
                               __ATOMIC_RELAXED, __HIP_MEMORY_SCOPE_AGENT);
            Hs[(size_t)t * HDIM + r0 + lane] = hn;   // consumed by next dispatch
        }
    }
}

// ---------------------------------------------------------------------------
// Row softmax over EDIM=2048: one block (256 threads) per row.
// ---------------------------------------------------------------------------
__global__ __launch_bounds__(256) void softmax_rows(
    const float* __restrict__ logits, float* __restrict__ out)
{
    const int row = blockIdx.x;
    const float4* in4 = (const float4*)(logits + (size_t)row * EDIM);
    float4* out4 = (float4*)(out + (size_t)row * EDIM);

    float4 v0 = in4[threadIdx.x];
    float4 v1 = in4[threadIdx.x + 256];

    float m = fmaxf(fmaxf(fmaxf(v0.x, v0.y), fmaxf(v0.z, v0.w)),
                    fmaxf(fmaxf(v1.x, v1.y), fmaxf(v1.z, v1.w)));
    #pragma unroll
    for (int off = 32; off > 0; off >>= 1) m = fmaxf(m, __shfl_xor(m, off));

    __shared__ float red[4];
    if ((threadIdx.x & 63) == 0) red[threadIdx.x >> 6] = m;
    __syncthreads();
    m = fmaxf(fmaxf(red[0], red[1]), fmaxf(red[2], red[3]));
    __syncthreads();

    float e[8];
    e[0] = expf(v0.x - m); e[1] = expf(v0.y - m);
    e[2] = expf(v0.z - m); e[3] = expf(v0.w - m);
    e[4] = expf(v1.x - m); e[5] = expf(v1.y - m);
    e[6] = expf(v1.z - m); e[7] = expf(v1.w - m);

    float s = e[0] + e[1] + e[2] + e[3] + e[4] + e[5] + e[6] + e[7];
    #pragma unroll
    for (int off = 32; off > 0; off >>= 1) s += __shfl_xor(s, off);
    if ((threadIdx.x & 63) == 0) red[threadIdx.x >> 6] = s;
    __syncthreads();
    s = red[0] + red[1] + red[2] + red[3];

    float inv = 1.0f / s;
    out4[threadIdx.x]       = make_float4(e[0] * inv, e[1] * inv, e[2] * inv, e[3] * inv);
    out4[threadIdx.x + 256] = make_float4(e[4] * inv, e[5] * inv, e[6] * inv, e[7] * inv);
}

__global__ void copy_vec(const float* __restrict__ src, float* __restrict__ dst, int n)
{
    int i = blockIdx.x * blockDim.x + threadIdx.x;
    if (i < n) dst[i] = src[i];
}

// ---------------------------------------------------------------------------
extern "C" void kernel_launch(void* const* d_in, const int* in_sizes, int n_in,
                              void* d_out, int out_size, void* d_ws, size_t ws_size,
                              hipStream_t stream)
{
    const float* x  = (const float*)d_in[0];   // [T_SEQ][EDIM]
    const float* Wh = (const float*)d_in[1];   // [HDIM][HDIM]
    const float* Wx = (const float*)d_in[2];   // [HDIM][EDIM]
    const float* Wy = (const float*)d_in[3];   // [EDIM][HDIM]
    const float* Bh = (const float*)d_in[4];   // [HDIM]
    const float* By = (const float*)d_in[5];   // [EDIM]

    float* out    = (float*)d_out;
    float* hfinal = out;                 // [HDIM]
    float* hs     = out + HDIM;          // [T_SEQ][HDIM]: holds hs, then probs

    float* xp   = (float*)d_ws;                                   // [T_SEQ][HDIM]
    u64*   hbuf = (u64*)((char*)d_ws + (size_t)T_SEQ * HDIM * 4); // [2][HDIM]
    float* logits = xp;                  // reuse (xp dead after recurrence)

    // clear tagged h buffers so replays never see stale tags
    hipMemsetAsync(hbuf, 0, 2 * HDIM * sizeof(u64), stream);

    // Phase 1: xp = x @ Wx^T + Bh
    gemm_nt_bias<<<dim3(HDIM / 64, T_SEQ / 64), 256, 0, stream>>>(
        x, Wx, Bh, xp, T_SEQ, HDIM, EDIM);

    // Phase 2: recurrence — cooperative launch only to guarantee co-residency
    int T = T_SEQ;
    const float* xp_c = xp;
    void* args[] = {(void*)&Wh, (void*)&xp_c, (void*)&hs, (void*)&hbuf, (void*)&T};
    hipLaunchCooperativeKernel((void*)rnn_recurrence, dim3(RBLK), dim3(512),
                               args, 0, stream);

    // Phase 3: logits = hs @ Wy^T + By
    gemm_nt_bias<<<dim3(EDIM / 64, T_SEQ / 64), 256, 0, stream>>>(
        hs, Wy, By, logits, T_SEQ, EDIM, HDIM);

    // Phase 4: h_final = hs[T-1] (before softmax overwrites hs region)
    copy_vec<<<dim3(HDIM / 256), 256, 0, stream>>>(
        hs + (size_t)(T_SEQ - 1) * HDIM, hfinal, HDIM);

    // Phase 5: softmax rows: logits (ws) -> output region of d_out
    softmax_rows<<<dim3(T_SEQ), 256, 0, stream>>>(logits, hs);
}

// Round 6
// 15314.172 us; speedup vs baseline: 33.6899x; 1.1647x over previous
//
#include <hip/hip_runtime.h>

#define T_SEQ 8192
#define HDIM  2048
#define EDIM  2048
#define RBLK  64                      // recurrence blocks
#define ROWS_PER_BLK (HDIM / RBLK)    // 32 rows/block, 4 rows/wave

typedef unsigned long long u64;
typedef __attribute__((ext_vector_type(4))) unsigned int u32x4;
typedef __attribute__((ext_vector_type(4))) float f32x4;

// 16B agent-coherent loads (bypass L1/L2, serviced at L3/MALL)
__device__ inline void poll_pair(const u64* p0, const u64* p1, u32x4& a, u32x4& b) {
    asm volatile("global_load_dwordx4 %0, %2, off sc1\n\t"
                 "global_load_dwordx4 %1, %3, off sc1\n\t"
                 "s_waitcnt vmcnt(0)"
                 : "=v"(a), "=v"(b) : "v"(p0), "v"(p1) : "memory");
}

// Non-rematerializable 16B load: result MUST live in VGPRs (asm output).
__device__ inline f32x4 ld_w16(const float* p) {
    f32x4 r;
    asm volatile("global_load_dwordx4 %0, %1, off" : "=v"(r) : "v"(p));
    return r;
}

// ---------------------------------------------------------------------------
// GEMM (NT): C[m][n] = sum_k A[m][k] * B[n][k] + bias[n]
// ---------------------------------------------------------------------------
__global__ __launch_bounds__(256) void gemm_nt_bias(
    const float* __restrict__ A, const float* __restrict__ B,
    const float* __restrict__ bias, float* __restrict__ C,
    int M, int N, int K)
{
    constexpr int BK = 32;
    __shared__ float As[BK][64 + 4];
    __shared__ float Bs[BK][64 + 4];

    const int tx = threadIdx.x & 15;
    const int ty = threadIdx.x >> 4;
    const int m0 = blockIdx.y * 64;
    const int n0 = blockIdx.x * 64;

    float acc[4][4] = {};

    for (int kk = 0; kk < K; kk += BK) {
        #pragma unroll
        for (int p = 0; p < 8; ++p) {
            int idx = p * 256 + threadIdx.x;
            int r = idx >> 5;
            int c = idx & 31;
            As[c][r] = A[(size_t)(m0 + r) * K + kk + c];
            Bs[c][r] = B[(size_t)(n0 + r) * K + kk + c];
        }
        __syncthreads();
        #pragma unroll
        for (int k = 0; k < BK; ++k) {
            float4 a = *(const float4*)&As[k][ty * 4];
            float4 b = *(const float4*)&Bs[k][tx * 4];
            float av[4] = {a.x, a.y, a.z, a.w};
            float bv[4] = {b.x, b.y, b.z, b.w};
            #pragma unroll
            for (int i = 0; i < 4; ++i)
                #pragma unroll
                for (int j = 0; j < 4; ++j)
                    acc[i][j] = fmaf(av[i], bv[j], acc[i][j]);
        }
        __syncthreads();
    }

    float4 bb = *(const float4*)&bias[n0 + tx * 4];
    float bvv[4] = {bb.x, bb.y, bb.z, bb.w};
    #pragma unroll
    for (int i = 0; i < 4; ++i) {
        float4 o;
        o.x = acc[i][0] + bvv[0];
        o.y = acc[i][1] + bvv[1];
        o.z = acc[i][2] + bvv[2];
        o.w = acc[i][3] + bvv[3];
        *(float4*)&C[(size_t)(m0 + ty * 4 + i) * N + n0 + tx * 4] = o;
    }
}

// ---------------------------------------------------------------------------
// Recurrence, 64 blocks x 512 threads. Wave w of block b owns rows
// b*32 + w*4 .. +3. W_h loaded via asm (non-remat) -> 128 VGPRs resident.
//
// Sync: hbuf[2][HDIM] of u64 (tag<<32 | f32bits). Writers use relaxed
// agent-scope atomic EXCHANGE: atomics execute at the MALL's atomic units,
// pinning the lines in the memory-side cache so reader polls (sc1 dwordx4)
// hit L3 instead of round-tripping to DRAM (R5: ~450MB of poll FETCH).
// Overwrite of the recycled buffer is safe: a wave's tag-t store
// value-depends on ALL its step-(t-1) loads, and poll success requires all
// 2048 tag-t words.
// ---------------------------------------------------------------------------
__global__ __launch_bounds__(512, 1) void rnn_recurrence(
    const float* __restrict__ Wh, const float* __restrict__ xp,
    float* __restrict__ Hs, u64* __restrict__ hbuf, int T)
{
    const int tid  = threadIdx.x;
    const int lane = tid & 63;
    const int wid  = tid >> 6;                              // 0..7
    const int r0   = blockIdx.x * ROWS_PER_BLK + wid * 4;   // wave's first row

    const float* wr0 = Wh + (size_t)(r0 + 0) * HDIM + lane * 4;
    const float* wr1 = Wh + (size_t)(r0 + 1) * HDIM + lane * 4;
    const float* wr2 = Wh + (size_t)(r0 + 2) * HDIM + lane * 4;
    const float* wr3 = Wh + (size_t)(r0 + 3) * HDIM + lane * 4;

    // 32 asm-loaded float4 = 128 VGPRs of W_h, register-resident (non-remat)
    f32x4 w00 = ld_w16(wr0 + 0*256), w01 = ld_w16(wr0 + 1*256), w02 = ld_w16(wr0 + 2*256), w03 = ld_w16(wr0 + 3*256);
    f32x4 w04 = ld_w16(wr0 + 4*256), w05 = ld_w16(wr0 + 5*256), w06 = ld_w16(wr0 + 6*256), w07 = ld_w16(wr0 + 7*256);
    f32x4 w10 = ld_w16(wr1 + 0*256), w11 = ld_w16(wr1 + 1*256), w12 = ld_w16(wr1 + 2*256), w13 = ld_w16(wr1 + 3*256);
    f32x4 w14 = ld_w16(wr1 + 4*256), w15 = ld_w16(wr1 + 5*256), w16 = ld_w16(wr1 + 6*256), w17 = ld_w16(wr1 + 7*256);
    f32x4 w20 = ld_w16(wr2 + 0*256), w21 = ld_w16(wr2 + 1*256), w22 = ld_w16(wr2 + 2*256), w23 = ld_w16(wr2 + 3*256);
    f32x4 w24 = ld_w16(wr2 + 4*256), w25 = ld_w16(wr2 + 5*256), w26 = ld_w16(wr2 + 6*256), w27 = ld_w16(wr2 + 7*256);
    f32x4 w30 = ld_w16(wr3 + 0*256), w31 = ld_w16(wr3 + 1*256), w32 = ld_w16(wr3 + 2*256), w33 = ld_w16(wr3 + 3*256);
    f32x4 w34 = ld_w16(wr3 + 4*256), w35 = ld_w16(wr3 + 5*256), w36 = ld_w16(wr3 + 6*256), w37 = ld_w16(wr3 + 7*256);
    asm volatile("s_waitcnt vmcnt(0)" ::: "memory");

    __shared__ float hsm[HDIM];

    for (int t = 0; t < T; ++t) {
        // prefetch this step's xp before any poll (latency hides under wait)
        float xq = 0.f;
        if (lane < 4) xq = xp[(size_t)t * HDIM + r0 + lane];

        float sv = 0.f;   // lane l (mod 4) ends up holding row r0+(l&3)'s sum
        if (t > 0) {
            const u64* hb = hbuf + (size_t)(t & 1) * HDIM;
            const unsigned tg = (unsigned)t;
            const u64* p0 = hb + 2 * tid;          // rows 2*tid, 2*tid+1
            const u64* p1 = hb + 1024 + 2 * tid;   // rows 1024+2*tid, +1

            u32x4 a, b;
            poll_pair(p0, p1, a, b);
            while ((a.y != tg) | (a.w != tg) | (b.y != tg) | (b.w != tg))
                poll_pair(p0, p1, a, b);           // one latency per round

            ((float2*)hsm)[tid] =
                make_float2(__uint_as_float(a.x), __uint_as_float(a.z));
            ((float2*)hsm)[tid + 512] =
                make_float2(__uint_as_float(b.x), __uint_as_float(b.z));
            __syncthreads();

            float s0 = 0.f, s1 = 0.f, s2 = 0.f, s3 = 0.f;
            #define RNN_STEP(IDX, WA, WB, WC, WD)                                   \
            {   float4 h4 = ((const float4*)hsm)[(IDX) * 64 + lane];                \
                s0 = fmaf(WA.x, h4.x, s0); s0 = fmaf(WA.y, h4.y, s0);               \
                s0 = fmaf(WA.z, h4.z, s0); s0 = fmaf(WA.w, h4.w, s0);               \
                s1 = fmaf(WB.x, h4.x, s1); s1 = fmaf(WB.y, h4.y, s1);               \
                s1 = fmaf(WB.z, h4.z, s1); s1 = fmaf(WB.w, h4.w, s1);               \
                s2 = fmaf(WC.x, h4.x, s2); s2 = fmaf(WC.y, h4.y, s2);               \
                s2 = fmaf(WC.z, h4.z, s2); s2 = fmaf(WC.w, h4.w, s2);               \
                s3 = fmaf(WD.x, h4.x, s3); s3 = fmaf(WD.y, h4.y, s3);               \
                s3 = fmaf(WD.z, h4.z, s3); s3 = fmaf(WD.w, h4.w, s3); }
            RNN_STEP(0, w00, w10, w20, w30)
            RNN_STEP(1, w01, w11, w21, w31)
            RNN_STEP(2, w02, w12, w22, w32)
            RNN_STEP(3, w03, w13, w23, w33)
            RNN_STEP(4, w04, w14, w24, w34)
            RNN_STEP(5, w05, w15, w25, w35)
            RNN_STEP(6, w06, w16, w26, w36)
            RNN_STEP(7, w07, w17, w27, w37)
            #undef RNN_STEP

            // 4-chain fold: 8 shfl total, lane l ends with row (l&3)'s sum.
            float fa = (lane & 1) ? s1 : s0;
            float fb = (lane & 1) ? s0 : s1;
            fa += __shfl_xor(fb, 1);
            float fc = (lane & 1) ? s3 : s2;
            float fd = (lane & 1) ? s2 : s3;
            fc += __shfl_xor(fd, 1);
            float fe = (lane & 2) ? fc : fa;
            float ff = (lane & 2) ? fa : fc;
            fe += __shfl_xor(ff, 2);
            #pragma unroll
            for (int off = 4; off < 64; off <<= 1) fe += __shfl_xor(fe, off);
            sv = fe;
            // no trailing barrier: next-step hsm writes are gated by the poll.
        }

        if (lane < 4) {
            float hn = tanhf(sv + xq);
            // tagged ATOMIC exchange first (pins line in MALL), Hs store after
            u64 pk = ((u64)(unsigned)(t + 1) << 32) | (u64)__float_as_uint(hn);
            (void)__hip_atomic_exchange(
                &hbuf[(size_t)((t + 1) & 1) * HDIM + r0 + lane], pk,
                __ATOMIC_RELAXED, __HIP_MEMORY_SCOPE_AGENT);
            Hs[(size_t)t * HDIM + r0 + lane] = hn;   // consumed by next dispatch
        }
    }
}

// ---------------------------------------------------------------------------
// Row softmax over EDIM=2048: one block (256 threads) per row.
// ---------------------------------------------------------------------------
__global__ __launch_bounds__(256) void softmax_rows(
    const float* __restrict__ logits, float* __restrict__ out)
{
    const int row = blockIdx.x;
    const float4* in4 = (const float4*)(logits + (size_t)row * EDIM);
    float4* out4 = (float4*)(out + (size_t)row * EDIM);

    float4 v0 = in4[threadIdx.x];
    float4 v1 = in4[threadIdx.x + 256];

    float m = fmaxf(fmaxf(fmaxf(v0.x, v0.y), fmaxf(v0.z, v0.w)),
                    fmaxf(fmaxf(v1.x, v1.y), fmaxf(v1.z, v1.w)));
    #pragma unroll
    for (int off = 32; off > 0; off >>= 1) m = fmaxf(m, __shfl_xor(m, off));

    __shared__ float red[4];
    if ((threadIdx.x & 63) == 0) red[threadIdx.x >> 6] = m;
    __syncthreads();
    m = fmaxf(fmaxf(red[0], red[1]), fmaxf(red[2], red[3]));
    __syncthreads();

    float e[8];
    e[0] = expf(v0.x - m); e[1] = expf(v0.y - m);
    e[2] = expf(v0.z - m); e[3] = expf(v0.w - m);
    e[4] = expf(v1.x - m); e[5] = expf(v1.y - m);
    e[6] = expf(v1.z - m); e[7] = expf(v1.w - m);

    float s = e[0] + e[1] + e[2] + e[3] + e[4] + e[5] + e[6] + e[7];
    #pragma unroll
    for (int off = 32; off > 0; off >>= 1) s += __shfl_xor(s, off);
    if ((threadIdx.x & 63) == 0) red[threadIdx.x >> 6] = s;
    __syncthreads();
    s = red[0] + red[1] + red[2] + red[3];

    float inv = 1.0f / s;
    out4[threadIdx.x]       = make_float4(e[0] * inv, e[1] * inv, e[2] * inv, e[3] * inv);
    out4[threadIdx.x + 256] = make_float4(e[4] * inv, e[5] * inv, e[6] * inv, e[7] * inv);
}

__global__ void copy_vec(const float* __restrict__ src, float* __restrict__ dst, int n)
{
    int i = blockIdx.x * blockDim.x + threadIdx.x;
    if (i < n) dst[i] = src[i];
}

// ---------------------------------------------------------------------------
extern "C" void kernel_launch(void* const* d_in, const int* in_sizes, int n_in,
                              void* d_out, int out_size, void* d_ws, size_t ws_size,
                              hipStream_t stream)
{
    const float* x  = (const float*)d_in[0];   // [T_SEQ][EDIM]
    const float* Wh = (const float*)d_in[1];   // [HDIM][HDIM]
    const float* Wx = (const float*)d_in[2];   // [HDIM][EDIM]
    const float* Wy = (const float*)d_in[3];   // [EDIM][HDIM]
    const float* Bh = (const float*)d_in[4];   // [HDIM]
    const float* By = (const float*)d_in[5];   // [EDIM]

    float* out    = (float*)d_out;
    float* hfinal = out;                 // [HDIM]
    float* hs     = out + HDIM;          // [T_SEQ][HDIM]: holds hs, then probs

    float* xp   = (float*)d_ws;                                   // [T_SEQ][HDIM]
    u64*   hbuf = (u64*)((char*)d_ws + (size_t)T_SEQ * HDIM * 4); // [2][HDIM]
    float* logits = xp;                  // reuse (xp dead after recurrence)

    // clear tagged h buffers so replays never see stale tags
    hipMemsetAsync(hbuf, 0, 2 * HDIM * sizeof(u64), stream);

    // Phase 1: xp = x @ Wx^T + Bh
    gemm_nt_bias<<<dim3(HDIM / 64, T_SEQ / 64), 256, 0, stream>>>(
        x, Wx, Bh, xp, T_SEQ, HDIM, EDIM);

    // Phase 2: recurrence — cooperative launch only to guarantee co-residency
    int T = T_SEQ;
    const float* xp_c = xp;
    void* args[] = {(void*)&Wh, (void*)&xp_c, (void*)&hs, (void*)&hbuf, (void*)&T};
    hipLaunchCooperativeKernel((void*)rnn_recurrence, dim3(RBLK), dim3(512),
                               args, 0, stream);

    // Phase 3: logits = hs @ Wy^T + By
    gemm_nt_bias<<<dim3(EDIM / 64, T_SEQ / 64), 256, 0, stream>>>(
        hs, Wy, By, logits, T_SEQ, EDIM, HDIM);

    // Phase 4: h_final = hs[T-1] (before softmax overwrites hs region)
    copy_vec<<<dim3(HDIM / 256), 256, 0, stream>>>(
        hs + (size_t)(T_SEQ - 1) * HDIM, hfinal, HDIM);

    // Phase 5: softmax rows: logits (ws) -> output region of d_out
    softmax_rows<<<dim3(T_SEQ), 256, 0, stream>>>(logits, hs);
}